// Round 10
// baseline (560.780 us; speedup 1.0000x reference)
//
#include <hip/hip_runtime.h>

#define D 128
#define EPSV 1e-5f

typedef _Float16 f16;
typedef __attribute__((ext_vector_type(8))) _Float16 f16x8;
typedef __attribute__((ext_vector_type(4))) _Float16 f16x4;
typedef __attribute__((ext_vector_type(4))) float f32x4;

// ---------- fold BN of prev layer into W (stats folded inline) ----------
__global__ void fold_kernel(const float* __restrict__ W, const float* __restrict__ stats,
                            const float* __restrict__ gamma, const float* __restrict__ beta,
                            float Ninv, int use_id,
                            f16* __restrict__ Wfo, float* __restrict__ shW) {
    const int o = blockIdx.x;
    const int k = threadIdx.x;
    float w = W[o * D + k];
    float sc = 1.0f, sh = 0.0f;
    if (!use_id) {
        float mu = stats[k] * Ninv;
        float var = stats[D + k] * Ninv - mu * mu;
        float inv = rsqrtf(var + EPSV);
        sc = gamma[k] * inv;
        sh = beta[k] - mu * sc;
    }
    Wfo[o * D + k] = (f16)(w * sc);
    float v = sh * w;
    #pragma unroll
    for (int off = 1; off < 64; off <<= 1) v += __shfl_xor(v, off, 64);
    __shared__ float red[2];
    if ((k & 63) == 0) red[k >> 6] = v;
    __syncthreads();
    if (k == 0) shW[o] = red[0] + red[1];
}

// ================= bucketized CSR build =================
__global__ __launch_bounds__(256) void bcount_kernel(const int* __restrict__ col,
                                                     int* __restrict__ gb, int E, int seg) {
    __shared__ int s[4096];
    for (int j = threadIdx.x; j < seg; j += 256) s[j] = 0;
    __syncthreads();
    int i = blockIdx.x * 256 + threadIdx.x;
    const int stride = gridDim.x * 256;
    for (; i < E; i += stride) {
        int b = col[i] >> 8;
        int p = (i >> 8) & 7;
        atomicAdd(&s[b * 8 + p], 1);
    }
    __syncthreads();
    for (int j = threadIdx.x; j < seg; j += 256)
        if (s[j]) atomicAdd(&gb[j], s[j]);
}

__global__ __launch_bounds__(1024) void bscan_kernel(const int* __restrict__ gb,
                                                     int* __restrict__ soff,
                                                     int* __restrict__ cur) {
    __shared__ int s[1024];
    const int tid = threadIdx.x;
    const int base = tid * 4;
    int g0 = gb[base], g1 = gb[base + 1], g2 = gb[base + 2], g3 = gb[base + 3];
    int my = g0 + g1 + g2 + g3;
    s[tid] = my;
    __syncthreads();
    for (int off = 1; off < 1024; off <<= 1) {
        int t = (tid >= off) ? s[tid - off] : 0;
        __syncthreads();
        s[tid] += t;
        __syncthreads();
    }
    int ex = s[tid] - my;
    soff[base] = ex;           cur[(base + 0) * 16] = ex;  ex += g0;
    soff[base + 1] = ex;       cur[(base + 1) * 16] = ex;  ex += g1;
    soff[base + 2] = ex;       cur[(base + 2) * 16] = ex;  ex += g2;
    soff[base + 3] = ex;       cur[(base + 3) * 16] = ex;
    if (tid == 1023) soff[4096] = s[1023];
}

__global__ __launch_bounds__(256) void bfill_kernel(const int* __restrict__ row,
                                                    const int* __restrict__ col,
                                                    int* __restrict__ cur,
                                                    int* __restrict__ bpairs, int E) {
    int i = blockIdx.x * 256 + threadIdx.x;
    const int stride = gridDim.x * 256;   // gridDim %8==0 keeps p == (i>>8)&7
    for (; i < E; i += stride) {
        int c = col[i];
        int b = c >> 8;
        int p = (i >> 8) & 7;
        int pos = atomicAdd(&cur[(b * 8 + p) * 16], 1);
        bpairs[pos] = (int)(((unsigned)(c & 255) << 24) | (unsigned)row[i]);
    }
}

// ---- merged: per-bucket degree + CSR offsets (LDS scan) + dis + tile degree-sort
//      (nodeinfo) + srcs fill. bucket b == node tile [b*256, b*256+256). ----
__global__ __launch_bounds__(256) void build_kernel(
    const int* __restrict__ bpairs, const int* __restrict__ soff,
    float* __restrict__ dis, int4* __restrict__ nodeinfo,
    int* __restrict__ srcs, int N)
{
    __shared__ int dc[256];     // degree count, later srcs cursor
    __shared__ int pf[256];     // scan scratch
    __shared__ int cur2[256];
    const int b = blockIdx.x;
    const int tid = threadIdx.x;
    dc[tid] = 0;
    __syncthreads();
    const int s0 = soff[b * 8], s1 = soff[(b + 1) * 8];
    for (int k = s0 + tid; k < s1; k += 256)
        atomicAdd(&dc[(unsigned)bpairs[k] >> 24], 1);
    __syncthreads();
    const int dv = dc[tid];
    // inclusive scan of dv
    pf[tid] = dv;
    __syncthreads();
    for (int off = 1; off < 256; off <<= 1) {
        int t = (tid >= off) ? pf[tid - off] : 0;
        __syncthreads();
        pf[tid] += t;
        __syncthreads();
    }
    const int myoff = s0 + pf[tid] - dv;     // CSR start for node c
    const int c = (b << 8) + tid;
    const float disv = rsqrtf((float)dv + 1.0f);   // +1 = self loop
    if (c < N) dis[c] = disv;
    // tile-local degree-descending sort -> nodeinfo
    __syncthreads();
    pf[tid] = 0;                 // reuse as hist
    __syncthreads();
    int bin = 0;
    if (c < N) {
        bin = 255 - min(dv, 255);
        atomicAdd(&pf[bin], 1);
    }
    __syncthreads();
    int hv = pf[tid];
    cur2[tid] = hv;
    __syncthreads();
    for (int off = 1; off < 256; off <<= 1) {
        int t = (tid >= off) ? cur2[tid - off] : 0;
        __syncthreads();
        cur2[tid] += t;
        __syncthreads();
    }
    cur2[tid] -= hv;             // exclusive
    __syncthreads();
    if (c < N) {
        int pos = atomicAdd(&cur2[bin], 1);
        nodeinfo[b * 256 + pos] = make_int4(c, myoff, dv, __float_as_int(disv));
    }
    // srcs fill (cursor = myoff, stored in dc)
    __syncthreads();
    dc[tid] = myoff;
    __syncthreads();
    for (int k = s0 + tid; k < s1; k += 256) {
        int pk = bpairs[k];
        int pos = atomicAdd(&dc[(unsigned)pk >> 24], 1);
        srcs[pos] = pk & 0x00FFFFFF;
    }
}

// ================= per-layer kernels =================

// ---- MFMA GEMM; xf32 != null => convert-on-load (layer 0); block 0 zeroes stats ----
__global__ __launch_bounds__(256) void gemm_kernel(
    const f16* __restrict__ xh, const float* __restrict__ xf32,
    const f16* __restrict__ Wfo, const float* __restrict__ shW,
    const float* __restrict__ dis, f16* __restrict__ h,
    float* __restrict__ stats, int N, int nrg)
{
    if (blockIdx.x == 0) stats[threadIdx.x] = 0.0f;   // 256 threads == 2*D

    const int lane = threadIdx.x & 63;
    const int l15 = lane & 15;
    const int lh = lane >> 4;

    f16x8 af[8][4];
    #pragma unroll
    for (int t = 0; t < 8; t++)
        #pragma unroll
        for (int kb = 0; kb < 4; kb++)
            af[t][kb] = *reinterpret_cast<const f16x8*>(
                &Wfo[(t * 16 + l15) * D + kb * 32 + lh * 8]);

    const int wid = (blockIdx.x * blockDim.x + threadIdx.x) >> 6;
    const int nwaves = (gridDim.x * blockDim.x) >> 6;

    for (int rg = wid; rg < nrg; rg += nwaves) {
        int row = rg * 16 + l15;
        int rrow = min(row, N - 1);
        f16x8 bf[4];
        if (xf32) {
            #pragma unroll
            for (int kb = 0; kb < 4; kb++) {
                const float* p = &xf32[(long long)rrow * D + kb * 32 + lh * 8];
                float4 u0 = *reinterpret_cast<const float4*>(p);
                float4 u1 = *reinterpret_cast<const float4*>(p + 4);
                f16x8 b;
                b[0] = (f16)u0.x; b[1] = (f16)u0.y; b[2] = (f16)u0.z; b[3] = (f16)u0.w;
                b[4] = (f16)u1.x; b[5] = (f16)u1.y; b[6] = (f16)u1.z; b[7] = (f16)u1.w;
                bf[kb] = b;
            }
        } else {
            #pragma unroll
            for (int kb = 0; kb < 4; kb++)
                bf[kb] = *reinterpret_cast<const f16x8*>(
                    &xh[(long long)rrow * D + kb * 32 + lh * 8]);
        }
        float d = dis[rrow];
        bool ok = (row < N);

        #pragma unroll
        for (int t = 0; t < 8; t++) {
            f32x4 acc = {0.0f, 0.0f, 0.0f, 0.0f};
            #pragma unroll
            for (int kb = 0; kb < 4; kb++)
                acc = __builtin_amdgcn_mfma_f32_16x16x32_f16(af[t][kb], bf[kb], acc, 0, 0, 0);
            int o0 = t * 16 + lh * 4;
            float4 sw = *reinterpret_cast<const float4*>(&shW[o0]);
            f16x4 ov;
            ov[0] = (f16)(d * (acc[0] + sw.x));
            ov[1] = (f16)(d * (acc[1] + sw.y));
            ov[2] = (f16)(d * (acc[2] + sw.z));
            ov[3] = (f16)(d * (acc[3] + sw.w));
            if (ok)
                *reinterpret_cast<f16x4*>(&h[(long long)row * D + o0]) = ov;
        }
    }
}

// ---- fused gather + finalize: 128-thread blocks, 8 groups x 2 nodes,
//      descriptor prefetch, exactly 2 iterations per block ----
__global__ __launch_bounds__(128) void gather_kernel(
    const f16* __restrict__ h, const int4* __restrict__ nodeinfo,
    const int* __restrict__ srcs, const float* __restrict__ bias,
    f16* __restrict__ t, float* __restrict__ stats, int N, int E)
{
    const int tid = threadIdx.x;
    const int l16 = tid & 15;
    const int grp = tid >> 4;            // 8 groups, 2 nodes each per iter
    const int f8 = l16 * 8;
    float bv[8];
    {
        float4 ba = *reinterpret_cast<const float4*>(&bias[f8]);
        float4 bb = *reinterpret_cast<const float4*>(&bias[f8 + 4]);
        bv[0] = ba.x; bv[1] = ba.y; bv[2] = ba.z; bv[3] = ba.w;
        bv[4] = bb.x; bv[5] = bb.y; bv[6] = bb.z; bv[7] = bb.w;
    }
    float ssum[8] = {0, 0, 0, 0, 0, 0, 0, 0}, ssq[8] = {0, 0, 0, 0, 0, 0, 0, 0};

    int ci = blockIdx.x * 16 + grp * 2;
    const int cstride = gridDim.x * 16;
    const int4 zero4 = make_int4(0, 0, 0, 0);
    int4 niA = (ci < N) ? nodeinfo[ci] : zero4;
    int4 niB = (ci + 1 < N) ? nodeinfo[ci + 1] : zero4;

    for (; ci < N; ci += cstride) {
        // prefetch next iteration's descriptors
        const int cin = ci + cstride;
        int4 niA_n = (cin < N) ? nodeinfo[cin] : zero4;
        int4 niB_n = (cin + 1 < N) ? nodeinfo[cin + 1] : zero4;

        const bool v1 = (ci + 1 < N);
        const int c0 = niA.x, k00 = niA.y, d0 = niA.z;
        const float dis0 = __int_as_float(niA.w);
        const int c1 = v1 ? niB.x : c0;
        const int k10 = v1 ? niB.y : 0;
        const int d1 = v1 ? niB.z : 0;
        const float dis1 = v1 ? __int_as_float(niB.w) : 0.0f;

        f16x8 s0v = *reinterpret_cast<const f16x8*>(&h[(long long)c0 * D + f8]);
        f16x8 s1v = *reinterpret_cast<const f16x8*>(&h[(long long)c1 * D + f8]);
        float a0[8], a1[8];
        #pragma unroll
        for (int m = 0; m < 8; m++) { a0[m] = (float)s0v[m]; a1[m] = (float)s1v[m]; }

        const int maxd = max(d0, d1);
        for (int kb = 0; kb < maxd; kb += 16) {
            int i0 = min(k00 + kb + l16, E - 1);
            int i1 = min(k10 + kb + l16, E - 1);
            int rl0 = srcs[i0];
            int rl1 = srcs[i1];
            int cnt0 = min(16, d0 - kb);
            int cnt1 = min(16, d1 - kb);
            int cmax = max(cnt0, cnt1);
            for (int j = 0; j < cmax; j += 2) {
                int r00 = __shfl(rl0, j, 16);
                int r01 = __shfl(rl0, j + 1, 16);
                int r10 = __shfl(rl1, j, 16);
                int r11 = __shfl(rl1, j + 1, 16);
                float w00 = (j < cnt0) ? 1.0f : 0.0f;
                float w01 = (j + 1 < cnt0) ? 1.0f : 0.0f;
                float w10 = (j < cnt1) ? 1.0f : 0.0f;
                float w11 = (j + 1 < cnt1) ? 1.0f : 0.0f;
                f16x8 v00 = *reinterpret_cast<const f16x8*>(&h[(long long)r00 * D + f8]);
                f16x8 v01 = *reinterpret_cast<const f16x8*>(&h[(long long)r01 * D + f8]);
                f16x8 v10 = *reinterpret_cast<const f16x8*>(&h[(long long)r10 * D + f8]);
                f16x8 v11 = *reinterpret_cast<const f16x8*>(&h[(long long)r11 * D + f8]);
                #pragma unroll
                for (int m = 0; m < 8; m++) {
                    a0[m] = fmaf(w00, (float)v00[m], a0[m]);
                    a0[m] = fmaf(w01, (float)v01[m], a0[m]);
                    a1[m] = fmaf(w10, (float)v10[m], a1[m]);
                    a1[m] = fmaf(w11, (float)v11[m], a1[m]);
                }
            }
        }

        // finalize node 0
        {
            float tv[8], s = 0.0f;
            #pragma unroll
            for (int m = 0; m < 8; m++) { tv[m] = dis0 * a0[m] + bv[m]; s += tv[m]; }
            #pragma unroll
            for (int off = 1; off < 16; off <<= 1) s += __shfl_xor(s, off, 16);
            float mean = s * (1.0f / 128.0f);
            f16x8 ov;
            #pragma unroll
            for (int m = 0; m < 8; m++) {
                tv[m] -= mean;
                ov[m] = (f16)tv[m];
                ssum[m] += tv[m];
                ssq[m] += tv[m] * tv[m];
            }
            *reinterpret_cast<f16x8*>(&t[(long long)c0 * D + f8]) = ov;
        }
        // finalize node 1
        {
            float g = v1 ? 1.0f : 0.0f;
            float tv[8], s = 0.0f;
            #pragma unroll
            for (int m = 0; m < 8; m++) { tv[m] = dis1 * a1[m] + bv[m]; s += tv[m]; }
            #pragma unroll
            for (int off = 1; off < 16; off <<= 1) s += __shfl_xor(s, off, 16);
            float mean = s * (1.0f / 128.0f);
            f16x8 ov;
            #pragma unroll
            for (int m = 0; m < 8; m++) {
                tv[m] -= mean;
                ov[m] = (f16)tv[m];
                ssum[m] += g * tv[m];
                ssq[m] += g * tv[m] * tv[m];
            }
            if (v1)
                *reinterpret_cast<f16x8*>(&t[(long long)c1 * D + f8]) = ov;
        }
        niA = niA_n;
        niB = niB_n;
    }

    __shared__ float red[128 * 16];
    #pragma unroll
    for (int j = 0; j < 8; j++) {
        red[tid * 16 + j] = ssum[j];
        red[tid * 16 + 8 + j] = ssq[j];
    }
    __syncthreads();
    #pragma unroll
    for (int oo = 0; oo < 2; oo++) {
        const int o = tid + oo * 128;
        const int f = o & 127;
        const int sq = o >> 7;
        const int lf = f >> 3;
        const int j = f & 7;
        float v = 0;
        #pragma unroll
        for (int g = 0; g < 8; g++)
            v += red[(g * 16 + lf) * 16 + sq * 8 + j];
        unsafeAtomicAdd(&stats[o], v);
    }
}

// ---- final BN apply (stats folded inline): out(f32) = t*sc + sh ----
__global__ __launch_bounds__(256) void epi2_kernel(
    const f16* __restrict__ t, const float* __restrict__ stats,
    const float* __restrict__ gamma, const float* __restrict__ beta,
    float Ninv, float* __restrict__ out, long long total4)
{
    __shared__ float sc[D], sh[D];
    if (threadIdx.x < D) {
        int j = threadIdx.x;
        float mu = stats[j] * Ninv;
        float var = stats[D + j] * Ninv - mu * mu;
        float inv = rsqrtf(var + EPSV);
        float s = gamma[j] * inv;
        sc[j] = s;
        sh[j] = beta[j] - mu * s;
    }
    __syncthreads();
    long long i = (long long)blockIdx.x * blockDim.x + threadIdx.x;
    const long long stride = (long long)gridDim.x * blockDim.x;
    for (; i < total4; i += stride) {
        f16x4 v = reinterpret_cast<const f16x4*>(t)[i];
        int f0 = (int)((i * 4) & (D - 1));
        float4 o;
        o.x = (float)v[0] * sc[f0 + 0] + sh[f0 + 0];
        o.y = (float)v[1] * sc[f0 + 1] + sh[f0 + 1];
        o.z = (float)v[2] * sc[f0 + 2] + sh[f0 + 2];
        o.w = (float)v[3] * sc[f0 + 3] + sh[f0 + 3];
        reinterpret_cast<float4*>(out)[i] = o;
    }
}

extern "C" void kernel_launch(void* const* d_in, const int* in_sizes, int n_in,
                              void* d_out, int out_size, void* d_ws, size_t ws_size,
                              hipStream_t stream)
{
    const float* x_in  = (const float*)d_in[0];
    const int*   ei    = (const int*)d_in[1];
    const float* W     = (const float*)d_in[2];
    const float* bias  = (const float*)d_in[3];
    const float* gamma = (const float*)d_in[4];
    const float* beta  = (const float*)d_in[5];

    const int N = in_sizes[0] / D;
    const int E = in_sizes[1] / 2;
    const int L = in_sizes[2] / (D * D);
    const int* row = ei;           // source
    const int* col = ei + E;       // target
    const int NB = (N + 255) / 256;
    const int NBUCK = (N + 255) >> 8;
    const int seg = NBUCK * 8;
    const int nrg = (N + 15) / 16;

    // ws layout: [f16: tbuf | hbuf | Wfo] [f32: dis | stats | shW]
    //            [int4: nodeinfo] [int: srcs | gb | soff | cur | bpairs]
    f16* tbuf = (f16*)d_ws;
    f16* hbuf = tbuf + (size_t)N * D;
    f16* Wfo  = hbuf + (size_t)N * D;
    float* dis   = (float*)(Wfo + D * D);
    float* stats = dis + N;
    float* shW   = stats + 2 * D;
    size_t offf = (size_t)(shW + D - (float*)d_ws);
    offf = (offf + 3) & ~(size_t)3;                  // 16B align
    int4* nodeinfo = (int4*)((float*)d_ws + offf);
    int* srcs   = (int*)(nodeinfo + (size_t)NB * 256);
    int* gb     = srcs + (E + 16);
    int* soff   = gb + 4096;
    int* cur    = soff + 4097;
    int* bpairs = cur + 4096 * 16;

    // ---- CSR build (5 dispatches) ----
    hipMemsetAsync(gb, 0, 4096 * sizeof(int), stream);
    bcount_kernel<<<128, 256, 0, stream>>>(col, gb, E, seg);
    bscan_kernel<<<1, 1024, 0, stream>>>(gb, soff, cur);
    bfill_kernel<<<1024, 256, 0, stream>>>(row, col, cur, bpairs, E);
    build_kernel<<<NBUCK, 256, 0, stream>>>(bpairs, soff, dis, nodeinfo, srcs, N);

    const float Ninv = 1.0f / (float)N;
    const long long total4 = (long long)N * D / 4;
    const int gblocks = (N + 31) / 32;    // 16 nodes/iter, exactly 2 iterations

    fold_kernel<<<D, D, 0, stream>>>(W, stats, gamma, beta, Ninv, 1, Wfo, shW);

    for (int l = 0; l < L; l++) {
        gemm_kernel<<<512, 256, 0, stream>>>(
            tbuf, (l == 0) ? x_in : nullptr, Wfo, shW, dis, hbuf, stats, N, nrg);
        gather_kernel<<<gblocks, 128, 0, stream>>>(
            hbuf, nodeinfo, srcs, bias + (size_t)l * D, tbuf, stats, N, E);
        if (l < L - 1)
            fold_kernel<<<D, D, 0, stream>>>(
                W + (size_t)(l + 1) * D * D, stats, gamma + (size_t)(l + 1) * D,
                beta + (size_t)(l + 1) * D, Ninv, 0, Wfo, shW);
        else
            epi2_kernel<<<4096, 256, 0, stream>>>(
                tbuf, stats, gamma + (size_t)l * D, beta + (size_t)l * D,
                Ninv, (float*)d_out, total4);
    }
}

// Round 11
// 459.621 us; speedup vs baseline: 1.2201x; 1.2201x over previous
//
#include <hip/hip_runtime.h>

#define D 128
#define EPSV 1e-5f

typedef _Float16 f16;
typedef __attribute__((ext_vector_type(8))) _Float16 f16x8;
typedef __attribute__((ext_vector_type(4))) _Float16 f16x4;
typedef __attribute__((ext_vector_type(4))) float f32x4;

// ---------- fold BN of prev layer into W (stats folded inline) ----------
__global__ void fold_kernel(const float* __restrict__ W, const float* __restrict__ stats,
                            const float* __restrict__ gamma, const float* __restrict__ beta,
                            float Ninv, int use_id,
                            f16* __restrict__ Wfo, float* __restrict__ shW) {
    const int o = blockIdx.x;
    const int k = threadIdx.x;
    float w = W[o * D + k];
    float sc = 1.0f, sh = 0.0f;
    if (!use_id) {
        float mu = stats[k] * Ninv;
        float var = stats[D + k] * Ninv - mu * mu;
        float inv = rsqrtf(var + EPSV);
        sc = gamma[k] * inv;
        sh = beta[k] - mu * sc;
    }
    Wfo[o * D + k] = (f16)(w * sc);
    float v = sh * w;
    #pragma unroll
    for (int off = 1; off < 64; off <<= 1) v += __shfl_xor(v, off, 64);
    __shared__ float red[2];
    if ((k & 63) == 0) red[k >> 6] = v;
    __syncthreads();
    if (k == 0) shW[o] = red[0] + red[1];
}

// ================= bucketized CSR build =================
__global__ __launch_bounds__(256) void bcount_kernel(const int* __restrict__ col,
                                                     int* __restrict__ gb, int E, int seg) {
    __shared__ int s[4096];
    for (int j = threadIdx.x; j < seg; j += 256) s[j] = 0;
    __syncthreads();
    int i = blockIdx.x * 256 + threadIdx.x;
    const int stride = gridDim.x * 256;
    for (; i < E; i += stride) {
        int b = col[i] >> 8;
        int p = (i >> 8) & 7;
        atomicAdd(&s[b * 8 + p], 1);
    }
    __syncthreads();
    for (int j = threadIdx.x; j < seg; j += 256)
        if (s[j]) atomicAdd(&gb[j], s[j]);
}

__global__ __launch_bounds__(1024) void bscan_kernel(const int* __restrict__ gb,
                                                     int* __restrict__ soff,
                                                     int* __restrict__ cur) {
    __shared__ int s[1024];
    const int tid = threadIdx.x;
    const int base = tid * 4;
    int g0 = gb[base], g1 = gb[base + 1], g2 = gb[base + 2], g3 = gb[base + 3];
    int my = g0 + g1 + g2 + g3;
    s[tid] = my;
    __syncthreads();
    for (int off = 1; off < 1024; off <<= 1) {
        int t = (tid >= off) ? s[tid - off] : 0;
        __syncthreads();
        s[tid] += t;
        __syncthreads();
    }
    int ex = s[tid] - my;
    soff[base] = ex;           cur[(base + 0) * 16] = ex;  ex += g0;
    soff[base + 1] = ex;       cur[(base + 1) * 16] = ex;  ex += g1;
    soff[base + 2] = ex;       cur[(base + 2) * 16] = ex;  ex += g2;
    soff[base + 3] = ex;       cur[(base + 3) * 16] = ex;
    if (tid == 1023) soff[4096] = s[1023];
}

__global__ __launch_bounds__(256) void bfill_kernel(const int* __restrict__ row,
                                                    const int* __restrict__ col,
                                                    int* __restrict__ cur,
                                                    int* __restrict__ bpairs, int E) {
    int i = blockIdx.x * 256 + threadIdx.x;
    const int stride = gridDim.x * 256;   // gridDim %8==0 keeps p == (i>>8)&7
    for (; i < E; i += stride) {
        int c = col[i];
        int b = c >> 8;
        int p = (i >> 8) & 7;
        int pos = atomicAdd(&cur[(b * 8 + p) * 16], 1);
        bpairs[pos] = (int)(((unsigned)(c & 255) << 24) | (unsigned)row[i]);
    }
}

// ---- merged: per-bucket degree + CSR offsets (LDS scan) + dis + tile degree-sort
//      (nodeinfo) + srcs fill. bucket b == node tile [b*256, b*256+256). ----
__global__ __launch_bounds__(256) void build_kernel(
    const int* __restrict__ bpairs, const int* __restrict__ soff,
    float* __restrict__ dis, int4* __restrict__ nodeinfo,
    int* __restrict__ srcs, int N)
{
    __shared__ int dc[256];     // degree count, later srcs cursor
    __shared__ int pf[256];     // scan scratch
    __shared__ int cur2[256];
    const int b = blockIdx.x;
    const int tid = threadIdx.x;
    dc[tid] = 0;
    __syncthreads();
    const int s0 = soff[b * 8], s1 = soff[(b + 1) * 8];
    for (int k = s0 + tid; k < s1; k += 256)
        atomicAdd(&dc[(unsigned)bpairs[k] >> 24], 1);
    __syncthreads();
    const int dv = dc[tid];
    // inclusive scan of dv
    pf[tid] = dv;
    __syncthreads();
    for (int off = 1; off < 256; off <<= 1) {
        int t = (tid >= off) ? pf[tid - off] : 0;
        __syncthreads();
        pf[tid] += t;
        __syncthreads();
    }
    const int myoff = s0 + pf[tid] - dv;     // CSR start for node c
    const int c = (b << 8) + tid;
    const float disv = rsqrtf((float)dv + 1.0f);   // +1 = self loop
    if (c < N) dis[c] = disv;
    // tile-local degree-descending sort -> nodeinfo
    __syncthreads();
    pf[tid] = 0;                 // reuse as hist
    __syncthreads();
    int bin = 0;
    if (c < N) {
        bin = 255 - min(dv, 255);
        atomicAdd(&pf[bin], 1);
    }
    __syncthreads();
    int hv = pf[tid];
    cur2[tid] = hv;
    __syncthreads();
    for (int off = 1; off < 256; off <<= 1) {
        int t = (tid >= off) ? cur2[tid - off] : 0;
        __syncthreads();
        cur2[tid] += t;
        __syncthreads();
    }
    cur2[tid] -= hv;             // exclusive
    __syncthreads();
    if (c < N) {
        int pos = atomicAdd(&cur2[bin], 1);
        nodeinfo[b * 256 + pos] = make_int4(c, myoff, dv, __float_as_int(disv));
    }
    // srcs fill (cursor = myoff, stored in dc)
    __syncthreads();
    dc[tid] = myoff;
    __syncthreads();
    for (int k = s0 + tid; k < s1; k += 256) {
        int pk = bpairs[k];
        int pos = atomicAdd(&dc[(unsigned)pk >> 24], 1);
        srcs[pos] = pk & 0x00FFFFFF;
    }
}

// ================= per-layer kernels =================

// ---- MFMA GEMM; xf32 != null => convert-on-load (layer 0); block 0 zeroes stats ----
__global__ __launch_bounds__(256) void gemm_kernel(
    const f16* __restrict__ xh, const float* __restrict__ xf32,
    const f16* __restrict__ Wfo, const float* __restrict__ shW,
    const float* __restrict__ dis, f16* __restrict__ h,
    float* __restrict__ stats, int N, int nrg)
{
    if (blockIdx.x == 0) stats[threadIdx.x] = 0.0f;   // 256 threads == 2*D

    const int lane = threadIdx.x & 63;
    const int l15 = lane & 15;
    const int lh = lane >> 4;

    f16x8 af[8][4];
    #pragma unroll
    for (int t = 0; t < 8; t++)
        #pragma unroll
        for (int kb = 0; kb < 4; kb++)
            af[t][kb] = *reinterpret_cast<const f16x8*>(
                &Wfo[(t * 16 + l15) * D + kb * 32 + lh * 8]);

    const int wid = (blockIdx.x * blockDim.x + threadIdx.x) >> 6;
    const int nwaves = (gridDim.x * blockDim.x) >> 6;

    for (int rg = wid; rg < nrg; rg += nwaves) {
        int row = rg * 16 + l15;
        int rrow = min(row, N - 1);
        f16x8 bf[4];
        if (xf32) {
            #pragma unroll
            for (int kb = 0; kb < 4; kb++) {
                const float* p = &xf32[(long long)rrow * D + kb * 32 + lh * 8];
                float4 u0 = *reinterpret_cast<const float4*>(p);
                float4 u1 = *reinterpret_cast<const float4*>(p + 4);
                f16x8 b;
                b[0] = (f16)u0.x; b[1] = (f16)u0.y; b[2] = (f16)u0.z; b[3] = (f16)u0.w;
                b[4] = (f16)u1.x; b[5] = (f16)u1.y; b[6] = (f16)u1.z; b[7] = (f16)u1.w;
                bf[kb] = b;
            }
        } else {
            #pragma unroll
            for (int kb = 0; kb < 4; kb++)
                bf[kb] = *reinterpret_cast<const f16x8*>(
                    &xh[(long long)rrow * D + kb * 32 + lh * 8]);
        }
        float d = dis[rrow];
        bool ok = (row < N);

        #pragma unroll
        for (int t = 0; t < 8; t++) {
            f32x4 acc = {0.0f, 0.0f, 0.0f, 0.0f};
            #pragma unroll
            for (int kb = 0; kb < 4; kb++)
                acc = __builtin_amdgcn_mfma_f32_16x16x32_f16(af[t][kb], bf[kb], acc, 0, 0, 0);
            int o0 = t * 16 + lh * 4;
            float4 sw = *reinterpret_cast<const float4*>(&shW[o0]);
            f16x4 ov;
            ov[0] = (f16)(d * (acc[0] + sw.x));
            ov[1] = (f16)(d * (acc[1] + sw.y));
            ov[2] = (f16)(d * (acc[2] + sw.z));
            ov[3] = (f16)(d * (acc[3] + sw.w));
            if (ok)
                *reinterpret_cast<f16x4*>(&h[(long long)row * D + o0]) = ov;
        }
    }
}

// ---- fused gather + finalize: r7 config (256 thr, 16 groups x 2 nodes,
//      descriptor prefetch, exactly 2 iterations), padded LDS reduce ----
__global__ __launch_bounds__(256) void gather_kernel(
    const f16* __restrict__ h, const int4* __restrict__ nodeinfo,
    const int* __restrict__ srcs, const float* __restrict__ bias,
    f16* __restrict__ t, float* __restrict__ stats, int N, int E)
{
    const int tid = threadIdx.x;
    const int l16 = tid & 15;
    const int grp = tid >> 4;            // 16 groups, 2 nodes each per iter
    const int f8 = l16 * 8;
    float bv[8];
    {
        float4 ba = *reinterpret_cast<const float4*>(&bias[f8]);
        float4 bb = *reinterpret_cast<const float4*>(&bias[f8 + 4]);
        bv[0] = ba.x; bv[1] = ba.y; bv[2] = ba.z; bv[3] = ba.w;
        bv[4] = bb.x; bv[5] = bb.y; bv[6] = bb.z; bv[7] = bb.w;
    }
    float ssum[8] = {0, 0, 0, 0, 0, 0, 0, 0}, ssq[8] = {0, 0, 0, 0, 0, 0, 0, 0};

    int ci = blockIdx.x * 32 + grp * 2;
    const int cstride = gridDim.x * 32;
    const int4 zero4 = make_int4(0, 0, 0, 0);
    int4 niA = (ci < N) ? nodeinfo[ci] : zero4;
    int4 niB = (ci + 1 < N) ? nodeinfo[ci + 1] : zero4;

    for (; ci < N; ci += cstride) {
        // prefetch next iteration's descriptors
        const int cin = ci + cstride;
        int4 niA_n = (cin < N) ? nodeinfo[cin] : zero4;
        int4 niB_n = (cin + 1 < N) ? nodeinfo[cin + 1] : zero4;

        const bool v1 = (ci + 1 < N);
        const int c0 = niA.x, k00 = niA.y, d0 = niA.z;
        const float dis0 = __int_as_float(niA.w);
        const int c1 = v1 ? niB.x : c0;
        const int k10 = v1 ? niB.y : 0;
        const int d1 = v1 ? niB.z : 0;
        const float dis1 = v1 ? __int_as_float(niB.w) : 0.0f;

        f16x8 s0v = *reinterpret_cast<const f16x8*>(&h[(long long)c0 * D + f8]);
        f16x8 s1v = *reinterpret_cast<const f16x8*>(&h[(long long)c1 * D + f8]);
        float a0[8], a1[8];
        #pragma unroll
        for (int m = 0; m < 8; m++) { a0[m] = (float)s0v[m]; a1[m] = (float)s1v[m]; }

        const int maxd = max(d0, d1);
        for (int kb = 0; kb < maxd; kb += 16) {
            int i0 = min(k00 + kb + l16, E - 1);
            int i1 = min(k10 + kb + l16, E - 1);
            int rl0 = srcs[i0];
            int rl1 = srcs[i1];
            int cnt0 = min(16, d0 - kb);
            int cnt1 = min(16, d1 - kb);
            int cmax = max(cnt0, cnt1);
            for (int j = 0; j < cmax; j += 2) {
                int r00 = __shfl(rl0, j, 16);
                int r01 = __shfl(rl0, j + 1, 16);
                int r10 = __shfl(rl1, j, 16);
                int r11 = __shfl(rl1, j + 1, 16);
                float w00 = (j < cnt0) ? 1.0f : 0.0f;
                float w01 = (j + 1 < cnt0) ? 1.0f : 0.0f;
                float w10 = (j < cnt1) ? 1.0f : 0.0f;
                float w11 = (j + 1 < cnt1) ? 1.0f : 0.0f;
                f16x8 v00 = *reinterpret_cast<const f16x8*>(&h[(long long)r00 * D + f8]);
                f16x8 v01 = *reinterpret_cast<const f16x8*>(&h[(long long)r01 * D + f8]);
                f16x8 v10 = *reinterpret_cast<const f16x8*>(&h[(long long)r10 * D + f8]);
                f16x8 v11 = *reinterpret_cast<const f16x8*>(&h[(long long)r11 * D + f8]);
                #pragma unroll
                for (int m = 0; m < 8; m++) {
                    a0[m] = fmaf(w00, (float)v00[m], a0[m]);
                    a0[m] = fmaf(w01, (float)v01[m], a0[m]);
                    a1[m] = fmaf(w10, (float)v10[m], a1[m]);
                    a1[m] = fmaf(w11, (float)v11[m], a1[m]);
                }
            }
        }

        // finalize node 0
        {
            float tv[8], s = 0.0f;
            #pragma unroll
            for (int m = 0; m < 8; m++) { tv[m] = dis0 * a0[m] + bv[m]; s += tv[m]; }
            #pragma unroll
            for (int off = 1; off < 16; off <<= 1) s += __shfl_xor(s, off, 16);
            float mean = s * (1.0f / 128.0f);
            f16x8 ov;
            #pragma unroll
            for (int m = 0; m < 8; m++) {
                tv[m] -= mean;
                ov[m] = (f16)tv[m];
                ssum[m] += tv[m];
                ssq[m] += tv[m] * tv[m];
            }
            *reinterpret_cast<f16x8*>(&t[(long long)c0 * D + f8]) = ov;
        }
        // finalize node 1
        {
            float g = v1 ? 1.0f : 0.0f;
            float tv[8], s = 0.0f;
            #pragma unroll
            for (int m = 0; m < 8; m++) { tv[m] = dis1 * a1[m] + bv[m]; s += tv[m]; }
            #pragma unroll
            for (int off = 1; off < 16; off <<= 1) s += __shfl_xor(s, off, 16);
            float mean = s * (1.0f / 128.0f);
            f16x8 ov;
            #pragma unroll
            for (int m = 0; m < 8; m++) {
                tv[m] -= mean;
                ov[m] = (f16)tv[m];
                ssum[m] += g * tv[m];
                ssq[m] += g * tv[m] * tv[m];
            }
            if (v1)
                *reinterpret_cast<f16x8*>(&t[(long long)c1 * D + f8]) = ov;
        }
        niA = niA_n;
        niB = niB_n;
    }

    __shared__ float red[256 * 17];      // stride 17: kill bank conflicts
    #pragma unroll
    for (int j = 0; j < 8; j++) {
        red[tid * 17 + j] = ssum[j];
        red[tid * 17 + 8 + j] = ssq[j];
    }
    __syncthreads();
    const int o = tid;
    const int f = o & 127;
    const int sq = o >> 7;
    const int lf = f >> 3;
    const int j = f & 7;
    float v = 0;
    #pragma unroll
    for (int g = 0; g < 16; g++)
        v += red[(g * 16 + lf) * 17 + sq * 8 + j];
    unsafeAtomicAdd(&stats[o], v);
}

// ---- final BN apply (stats folded inline): out(f32) = t*sc + sh ----
__global__ __launch_bounds__(256) void epi2_kernel(
    const f16* __restrict__ t, const float* __restrict__ stats,
    const float* __restrict__ gamma, const float* __restrict__ beta,
    float Ninv, float* __restrict__ out, long long total4)
{
    __shared__ float sc[D], sh[D];
    if (threadIdx.x < D) {
        int j = threadIdx.x;
        float mu = stats[j] * Ninv;
        float var = stats[D + j] * Ninv - mu * mu;
        float inv = rsqrtf(var + EPSV);
        float s = gamma[j] * inv;
        sc[j] = s;
        sh[j] = beta[j] - mu * s;
    }
    __syncthreads();
    long long i = (long long)blockIdx.x * blockDim.x + threadIdx.x;
    const long long stride = (long long)gridDim.x * blockDim.x;
    for (; i < total4; i += stride) {
        f16x4 v = reinterpret_cast<const f16x4*>(t)[i];
        int f0 = (int)((i * 4) & (D - 1));
        float4 o;
        o.x = (float)v[0] * sc[f0 + 0] + sh[f0 + 0];
        o.y = (float)v[1] * sc[f0 + 1] + sh[f0 + 1];
        o.z = (float)v[2] * sc[f0 + 2] + sh[f0 + 2];
        o.w = (float)v[3] * sc[f0 + 3] + sh[f0 + 3];
        reinterpret_cast<float4*>(out)[i] = o;
    }
}

extern "C" void kernel_launch(void* const* d_in, const int* in_sizes, int n_in,
                              void* d_out, int out_size, void* d_ws, size_t ws_size,
                              hipStream_t stream)
{
    const float* x_in  = (const float*)d_in[0];
    const int*   ei    = (const int*)d_in[1];
    const float* W     = (const float*)d_in[2];
    const float* bias  = (const float*)d_in[3];
    const float* gamma = (const float*)d_in[4];
    const float* beta  = (const float*)d_in[5];

    const int N = in_sizes[0] / D;
    const int E = in_sizes[1] / 2;
    const int L = in_sizes[2] / (D * D);
    const int* row = ei;           // source
    const int* col = ei + E;       // target
    const int NBUCK = (N + 255) >> 8;
    const int seg = NBUCK * 8;
    const int nrg = (N + 15) / 16;

    // ws layout: [f16: tbuf | hbuf | Wfo] [f32: dis | stats | shW]
    //            [int4: nodeinfo] [int: srcs | gb | soff | cur | bpairs]
    f16* tbuf = (f16*)d_ws;
    f16* hbuf = tbuf + (size_t)N * D;
    f16* Wfo  = hbuf + (size_t)N * D;
    float* dis   = (float*)(Wfo + D * D);
    float* stats = dis + N;
    float* shW   = stats + 2 * D;
    size_t offf = (size_t)(shW + D - (float*)d_ws);
    offf = (offf + 3) & ~(size_t)3;                  // 16B align
    int4* nodeinfo = (int4*)((float*)d_ws + offf);
    int* srcs   = (int*)(nodeinfo + (size_t)NBUCK * 256);
    int* gb     = srcs + (E + 16);
    int* soff   = gb + 4096;
    int* cur    = soff + 4097;
    int* bpairs = cur + 4096 * 16;

    // ---- CSR build (5 dispatches) ----
    hipMemsetAsync(gb, 0, 4096 * sizeof(int), stream);
    bcount_kernel<<<128, 256, 0, stream>>>(col, gb, E, seg);
    bscan_kernel<<<1, 1024, 0, stream>>>(gb, soff, cur);
    bfill_kernel<<<1024, 256, 0, stream>>>(row, col, cur, bpairs, E);
    build_kernel<<<NBUCK, 256, 0, stream>>>(bpairs, soff, dis, nodeinfo, srcs, N);

    const float Ninv = 1.0f / (float)N;
    const long long total4 = (long long)N * D / 4;
    const int gblocks = (N + 63) / 64;    // 32 nodes/iter, exactly 2 iterations

    fold_kernel<<<D, D, 0, stream>>>(W, stats, gamma, beta, Ninv, 1, Wfo, shW);

    for (int l = 0; l < L; l++) {
        gemm_kernel<<<512, 256, 0, stream>>>(
            tbuf, (l == 0) ? x_in : nullptr, Wfo, shW, dis, hbuf, stats, N, nrg);
        gather_kernel<<<gblocks, 256, 0, stream>>>(
            hbuf, nodeinfo, srcs, bias + (size_t)l * D, tbuf, stats, N, E);
        if (l < L - 1)
            fold_kernel<<<D, D, 0, stream>>>(
                W + (size_t)(l + 1) * D * D, stats, gamma + (size_t)(l + 1) * D,
                beta + (size_t)(l + 1) * D, Ninv, 0, Wfo, shW);
        else
            epi2_kernel<<<4096, 256, 0, stream>>>(
                tbuf, stats, gamma + (size_t)l * D, beta + (size_t)l * D,
                Ninv, (float*)d_out, total4);
    }
}

// Round 12
// 446.346 us; speedup vs baseline: 1.2564x; 1.0297x over previous
//
#include <hip/hip_runtime.h>

#define D 128
#define EPSV 1e-5f

typedef _Float16 f16;
typedef __attribute__((ext_vector_type(8))) _Float16 f16x8;
typedef __attribute__((ext_vector_type(4))) _Float16 f16x4;
typedef __attribute__((ext_vector_type(4))) float f32x4;

// ---------- fold BN of prev layer into W (stats folded inline) ----------
__global__ void fold_kernel(const float* __restrict__ W, const float* __restrict__ stats,
                            const float* __restrict__ gamma, const float* __restrict__ beta,
                            float Ninv, int use_id,
                            f16* __restrict__ Wfo, float* __restrict__ shW) {
    const int o = blockIdx.x;
    const int k = threadIdx.x;
    float w = W[o * D + k];
    float sc = 1.0f, sh = 0.0f;
    if (!use_id) {
        float mu = stats[k] * Ninv;
        float var = stats[D + k] * Ninv - mu * mu;
        float inv = rsqrtf(var + EPSV);
        sc = gamma[k] * inv;
        sh = beta[k] - mu * sc;
    }
    Wfo[o * D + k] = (f16)(w * sc);
    float v = sh * w;
    #pragma unroll
    for (int off = 1; off < 64; off <<= 1) v += __shfl_xor(v, off, 64);
    __shared__ float red[2];
    if ((k & 63) == 0) red[k >> 6] = v;
    __syncthreads();
    if (k == 0) shW[o] = red[0] + red[1];
}

// ================= bucketized CSR build =================
__global__ __launch_bounds__(256) void bcount_kernel(const int* __restrict__ col,
                                                     int* __restrict__ gb, int E, int seg) {
    __shared__ int s[4096];
    for (int j = threadIdx.x; j < seg; j += 256) s[j] = 0;
    __syncthreads();
    int i = blockIdx.x * 256 + threadIdx.x;
    const int stride = gridDim.x * 256;
    for (; i < E; i += stride) {
        int b = col[i] >> 8;
        int p = (i >> 8) & 7;
        atomicAdd(&s[b * 8 + p], 1);
    }
    __syncthreads();
    for (int j = threadIdx.x; j < seg; j += 256)
        if (s[j]) atomicAdd(&gb[j], s[j]);
}

__global__ __launch_bounds__(1024) void bscan_kernel(const int* __restrict__ gb,
                                                     int* __restrict__ soff,
                                                     int* __restrict__ cur) {
    __shared__ int s[1024];
    const int tid = threadIdx.x;
    const int base = tid * 4;
    int g0 = gb[base], g1 = gb[base + 1], g2 = gb[base + 2], g3 = gb[base + 3];
    int my = g0 + g1 + g2 + g3;
    s[tid] = my;
    __syncthreads();
    for (int off = 1; off < 1024; off <<= 1) {
        int t = (tid >= off) ? s[tid - off] : 0;
        __syncthreads();
        s[tid] += t;
        __syncthreads();
    }
    int ex = s[tid] - my;
    soff[base] = ex;           cur[(base + 0) * 16] = ex;  ex += g0;
    soff[base + 1] = ex;       cur[(base + 1) * 16] = ex;  ex += g1;
    soff[base + 2] = ex;       cur[(base + 2) * 16] = ex;  ex += g2;
    soff[base + 3] = ex;       cur[(base + 3) * 16] = ex;
    if (tid == 1023) soff[4096] = s[1023];
}

__global__ __launch_bounds__(256) void bfill_kernel(const int* __restrict__ row,
                                                    const int* __restrict__ col,
                                                    int* __restrict__ cur,
                                                    int* __restrict__ bpairs, int E) {
    int i = blockIdx.x * 256 + threadIdx.x;
    const int stride = gridDim.x * 256;   // gridDim %8==0 keeps p == (i>>8)&7
    for (; i < E; i += stride) {
        int c = col[i];
        int b = c >> 8;
        int p = (i >> 8) & 7;
        int pos = atomicAdd(&cur[(b * 8 + p) * 16], 1);
        bpairs[pos] = (int)(((unsigned)(c & 255) << 24) | (unsigned)row[i]);
    }
}

// ---- merged: per-bucket degree + CSR offsets (LDS scan) + dis + tile degree-sort
//      (nodeinfo) + srcs fill. bucket b == node tile [b*256, b*256+256). ----
__global__ __launch_bounds__(256) void build_kernel(
    const int* __restrict__ bpairs, const int* __restrict__ soff,
    float* __restrict__ dis, int4* __restrict__ nodeinfo,
    int* __restrict__ srcs, int N)
{
    __shared__ int dc[256];     // degree count, later srcs cursor
    __shared__ int pf[256];     // scan scratch
    __shared__ int cur2[256];
    const int b = blockIdx.x;
    const int tid = threadIdx.x;
    dc[tid] = 0;
    __syncthreads();
    const int s0 = soff[b * 8], s1 = soff[(b + 1) * 8];
    for (int k = s0 + tid; k < s1; k += 256)
        atomicAdd(&dc[(unsigned)bpairs[k] >> 24], 1);
    __syncthreads();
    const int dv = dc[tid];
    // inclusive scan of dv
    pf[tid] = dv;
    __syncthreads();
    for (int off = 1; off < 256; off <<= 1) {
        int t = (tid >= off) ? pf[tid - off] : 0;
        __syncthreads();
        pf[tid] += t;
        __syncthreads();
    }
    const int myoff = s0 + pf[tid] - dv;     // CSR start for node c
    const int c = (b << 8) + tid;
    const float disv = rsqrtf((float)dv + 1.0f);   // +1 = self loop
    if (c < N) dis[c] = disv;
    // tile-local degree-descending sort -> nodeinfo
    __syncthreads();
    pf[tid] = 0;                 // reuse as hist
    __syncthreads();
    int bin = 0;
    if (c < N) {
        bin = 255 - min(dv, 255);
        atomicAdd(&pf[bin], 1);
    }
    __syncthreads();
    int hv = pf[tid];
    cur2[tid] = hv;
    __syncthreads();
    for (int off = 1; off < 256; off <<= 1) {
        int t = (tid >= off) ? cur2[tid - off] : 0;
        __syncthreads();
        cur2[tid] += t;
        __syncthreads();
    }
    cur2[tid] -= hv;             // exclusive
    __syncthreads();
    if (c < N) {
        int pos = atomicAdd(&cur2[bin], 1);
        nodeinfo[b * 256 + pos] = make_int4(c, myoff, dv, __float_as_int(disv));
    }
    // srcs fill (cursor = myoff, stored in dc)
    __syncthreads();
    dc[tid] = myoff;
    __syncthreads();
    for (int k = s0 + tid; k < s1; k += 256) {
        int pk = bpairs[k];
        int pos = atomicAdd(&dc[(unsigned)pk >> 24], 1);
        srcs[pos] = pk & 0x00FFFFFF;
    }
}

// ================= per-layer kernels =================

// ---- MFMA GEMM; xf32 != null => convert-on-load (layer 0); block 0 zeroes stats ----
__global__ __launch_bounds__(256) void gemm_kernel(
    const f16* __restrict__ xh, const float* __restrict__ xf32,
    const f16* __restrict__ Wfo, const float* __restrict__ shW,
    const float* __restrict__ dis, f16* __restrict__ h,
    float* __restrict__ stats, int N, int nrg)
{
    if (blockIdx.x == 0) stats[threadIdx.x] = 0.0f;   // 256 threads == 2*D

    const int lane = threadIdx.x & 63;
    const int l15 = lane & 15;
    const int lh = lane >> 4;

    f16x8 af[8][4];
    #pragma unroll
    for (int t = 0; t < 8; t++)
        #pragma unroll
        for (int kb = 0; kb < 4; kb++)
            af[t][kb] = *reinterpret_cast<const f16x8*>(
                &Wfo[(t * 16 + l15) * D + kb * 32 + lh * 8]);

    const int wid = (blockIdx.x * blockDim.x + threadIdx.x) >> 6;
    const int nwaves = (gridDim.x * blockDim.x) >> 6;

    for (int rg = wid; rg < nrg; rg += nwaves) {
        int row = rg * 16 + l15;
        int rrow = min(row, N - 1);
        f16x8 bf[4];
        if (xf32) {
            #pragma unroll
            for (int kb = 0; kb < 4; kb++) {
                const float* p = &xf32[(long long)rrow * D + kb * 32 + lh * 8];
                float4 u0 = *reinterpret_cast<const float4*>(p);
                float4 u1 = *reinterpret_cast<const float4*>(p + 4);
                f16x8 b;
                b[0] = (f16)u0.x; b[1] = (f16)u0.y; b[2] = (f16)u0.z; b[3] = (f16)u0.w;
                b[4] = (f16)u1.x; b[5] = (f16)u1.y; b[6] = (f16)u1.z; b[7] = (f16)u1.w;
                bf[kb] = b;
            }
        } else {
            #pragma unroll
            for (int kb = 0; kb < 4; kb++)
                bf[kb] = *reinterpret_cast<const f16x8*>(
                    &xh[(long long)rrow * D + kb * 32 + lh * 8]);
        }
        float d = dis[rrow];
        bool ok = (row < N);

        #pragma unroll
        for (int t = 0; t < 8; t++) {
            f32x4 acc = {0.0f, 0.0f, 0.0f, 0.0f};
            #pragma unroll
            for (int kb = 0; kb < 4; kb++)
                acc = __builtin_amdgcn_mfma_f32_16x16x32_f16(af[t][kb], bf[kb], acc, 0, 0, 0);
            int o0 = t * 16 + lh * 4;
            float4 sw = *reinterpret_cast<const float4*>(&shW[o0]);
            f16x4 ov;
            ov[0] = (f16)(d * (acc[0] + sw.x));
            ov[1] = (f16)(d * (acc[1] + sw.y));
            ov[2] = (f16)(d * (acc[2] + sw.z));
            ov[3] = (f16)(d * (acc[3] + sw.w));
            if (ok)
                *reinterpret_cast<f16x4*>(&h[(long long)row * D + o0]) = ov;
        }
    }
}

// ---- fused gather + finalize: 256 thr, 16 groups x 2 nodes, 2 iterations,
//      deep pipeline: prefetch next iter's descriptors + first srcs chunk + self rows ----
__global__ __launch_bounds__(256) void gather_kernel(
    const f16* __restrict__ h, const int4* __restrict__ nodeinfo,
    const int* __restrict__ srcs, const float* __restrict__ bias,
    f16* __restrict__ t, float* __restrict__ stats, int N, int E)
{
    const int tid = threadIdx.x;
    const int l16 = tid & 15;
    const int grp = tid >> 4;            // 16 groups, 2 nodes each per iter
    const int f8 = l16 * 8;
    float bv[8];
    {
        float4 ba = *reinterpret_cast<const float4*>(&bias[f8]);
        float4 bb = *reinterpret_cast<const float4*>(&bias[f8 + 4]);
        bv[0] = ba.x; bv[1] = ba.y; bv[2] = ba.z; bv[3] = ba.w;
        bv[4] = bb.x; bv[5] = bb.y; bv[6] = bb.z; bv[7] = bb.w;
    }
    float ssum[8] = {0, 0, 0, 0, 0, 0, 0, 0}, ssq[8] = {0, 0, 0, 0, 0, 0, 0, 0};

    int ci = blockIdx.x * 32 + grp * 2;
    const int cstride = gridDim.x * 32;
    const int4 zero4 = make_int4(0, 0, 0, 0);
    int4 niA = (ci < N) ? nodeinfo[ci] : zero4;
    int4 niB = (ci + 1 < N) ? nodeinfo[ci + 1] : zero4;
    // first-iteration deep prefetch
    int rl0_p = srcs[min(niA.y + l16, E - 1)];
    int rl1_p = srcs[min(((ci + 1 < N) ? niB.y : 0) + l16, E - 1)];
    f16x8 s0_p = *reinterpret_cast<const f16x8*>(&h[(long long)niA.x * D + f8]);
    f16x8 s1_p = *reinterpret_cast<const f16x8*>(
        &h[(long long)((ci + 1 < N) ? niB.x : niA.x) * D + f8]);

    for (; ci < N; ci += cstride) {
        // next-iteration prefetches: descriptors -> first srcs chunk + self rows
        const int cin = ci + cstride;
        int4 niA_n = (cin < N) ? nodeinfo[cin] : zero4;
        int4 niB_n = (cin + 1 < N) ? nodeinfo[cin + 1] : zero4;
        int rl0_pn = srcs[min(niA_n.y + l16, E - 1)];
        int rl1_pn = srcs[min(((cin + 1 < N) ? niB_n.y : 0) + l16, E - 1)];
        f16x8 s0_pn = *reinterpret_cast<const f16x8*>(&h[(long long)niA_n.x * D + f8]);
        f16x8 s1_pn = *reinterpret_cast<const f16x8*>(
            &h[(long long)((cin + 1 < N) ? niB_n.x : niA_n.x) * D + f8]);

        const bool v1 = (ci + 1 < N);
        const int c0 = niA.x, k00 = niA.y, d0 = niA.z;
        const float dis0 = __int_as_float(niA.w);
        const int c1 = v1 ? niB.x : c0;
        const int k10 = v1 ? niB.y : 0;
        const int d1 = v1 ? niB.z : 0;
        const float dis1 = v1 ? __int_as_float(niB.w) : 0.0f;

        float a0[8], a1[8];
        #pragma unroll
        for (int m = 0; m < 8; m++) { a0[m] = (float)s0_p[m]; a1[m] = (float)s1_p[m]; }

        const int maxd = max(d0, d1);
        // peeled kb = 0 chunk: consume prefetched srcs registers
        if (maxd > 0) {
            const int cnt0 = min(16, d0);
            const int cnt1 = min(16, d1);
            const int cmax = max(cnt0, cnt1);
            for (int j = 0; j < cmax; j += 2) {
                int r00 = __shfl(rl0_p, j, 16);
                int r01 = __shfl(rl0_p, j + 1, 16);
                int r10 = __shfl(rl1_p, j, 16);
                int r11 = __shfl(rl1_p, j + 1, 16);
                float w00 = (j < cnt0) ? 1.0f : 0.0f;
                float w01 = (j + 1 < cnt0) ? 1.0f : 0.0f;
                float w10 = (j < cnt1) ? 1.0f : 0.0f;
                float w11 = (j + 1 < cnt1) ? 1.0f : 0.0f;
                f16x8 v00 = *reinterpret_cast<const f16x8*>(&h[(long long)r00 * D + f8]);
                f16x8 v01 = *reinterpret_cast<const f16x8*>(&h[(long long)r01 * D + f8]);
                f16x8 v10 = *reinterpret_cast<const f16x8*>(&h[(long long)r10 * D + f8]);
                f16x8 v11 = *reinterpret_cast<const f16x8*>(&h[(long long)r11 * D + f8]);
                #pragma unroll
                for (int m = 0; m < 8; m++) {
                    a0[m] = fmaf(w00, (float)v00[m], a0[m]);
                    a0[m] = fmaf(w01, (float)v01[m], a0[m]);
                    a1[m] = fmaf(w10, (float)v10[m], a1[m]);
                    a1[m] = fmaf(w11, (float)v11[m], a1[m]);
                }
            }
        }
        // remaining chunks (rare: deg > 16)
        for (int kb = 16; kb < maxd; kb += 16) {
            int i0 = min(k00 + kb + l16, E - 1);
            int i1 = min(k10 + kb + l16, E - 1);
            int rl0 = srcs[i0];
            int rl1 = srcs[i1];
            int cnt0 = min(16, d0 - kb);
            int cnt1 = min(16, d1 - kb);
            int cmax = max(cnt0, cnt1);
            for (int j = 0; j < cmax; j += 2) {
                int r00 = __shfl(rl0, j, 16);
                int r01 = __shfl(rl0, j + 1, 16);
                int r10 = __shfl(rl1, j, 16);
                int r11 = __shfl(rl1, j + 1, 16);
                float w00 = (j < cnt0) ? 1.0f : 0.0f;
                float w01 = (j + 1 < cnt0) ? 1.0f : 0.0f;
                float w10 = (j < cnt1) ? 1.0f : 0.0f;
                float w11 = (j + 1 < cnt1) ? 1.0f : 0.0f;
                f16x8 v00 = *reinterpret_cast<const f16x8*>(&h[(long long)r00 * D + f8]);
                f16x8 v01 = *reinterpret_cast<const f16x8*>(&h[(long long)r01 * D + f8]);
                f16x8 v10 = *reinterpret_cast<const f16x8*>(&h[(long long)r10 * D + f8]);
                f16x8 v11 = *reinterpret_cast<const f16x8*>(&h[(long long)r11 * D + f8]);
                #pragma unroll
                for (int m = 0; m < 8; m++) {
                    a0[m] = fmaf(w00, (float)v00[m], a0[m]);
                    a0[m] = fmaf(w01, (float)v01[m], a0[m]);
                    a1[m] = fmaf(w10, (float)v10[m], a1[m]);
                    a1[m] = fmaf(w11, (float)v11[m], a1[m]);
                }
            }
        }

        // finalize node 0
        {
            float tv[8], s = 0.0f;
            #pragma unroll
            for (int m = 0; m < 8; m++) { tv[m] = dis0 * a0[m] + bv[m]; s += tv[m]; }
            #pragma unroll
            for (int off = 1; off < 16; off <<= 1) s += __shfl_xor(s, off, 16);
            float mean = s * (1.0f / 128.0f);
            f16x8 ov;
            #pragma unroll
            for (int m = 0; m < 8; m++) {
                tv[m] -= mean;
                ov[m] = (f16)tv[m];
                ssum[m] += tv[m];
                ssq[m] += tv[m] * tv[m];
            }
            *reinterpret_cast<f16x8*>(&t[(long long)c0 * D + f8]) = ov;
        }
        // finalize node 1
        {
            float g = v1 ? 1.0f : 0.0f;
            float tv[8], s = 0.0f;
            #pragma unroll
            for (int m = 0; m < 8; m++) { tv[m] = dis1 * a1[m] + bv[m]; s += tv[m]; }
            #pragma unroll
            for (int off = 1; off < 16; off <<= 1) s += __shfl_xor(s, off, 16);
            float mean = s * (1.0f / 128.0f);
            f16x8 ov;
            #pragma unroll
            for (int m = 0; m < 8; m++) {
                tv[m] -= mean;
                ov[m] = (f16)tv[m];
                ssum[m] += g * tv[m];
                ssq[m] += g * tv[m] * tv[m];
            }
            if (v1)
                *reinterpret_cast<f16x8*>(&t[(long long)c1 * D + f8]) = ov;
        }
        niA = niA_n;  niB = niB_n;
        rl0_p = rl0_pn;  rl1_p = rl1_pn;
        s0_p = s0_pn;  s1_p = s1_pn;
    }

    __shared__ float red[256 * 17];      // stride 17: conflict-free
    #pragma unroll
    for (int j = 0; j < 8; j++) {
        red[tid * 17 + j] = ssum[j];
        red[tid * 17 + 8 + j] = ssq[j];
    }
    __syncthreads();
    const int o = tid;
    const int f = o & 127;
    const int sq = o >> 7;
    const int lf = f >> 3;
    const int j = f & 7;
    float v = 0;
    #pragma unroll
    for (int g = 0; g < 16; g++)
        v += red[(g * 16 + lf) * 17 + sq * 8 + j];
    unsafeAtomicAdd(&stats[o], v);
}

// ---- final BN apply (stats folded inline): out(f32) = t*sc + sh ----
__global__ __launch_bounds__(256) void epi2_kernel(
    const f16* __restrict__ t, const float* __restrict__ stats,
    const float* __restrict__ gamma, const float* __restrict__ beta,
    float Ninv, float* __restrict__ out, long long total4)
{
    __shared__ float sc[D], sh[D];
    if (threadIdx.x < D) {
        int j = threadIdx.x;
        float mu = stats[j] * Ninv;
        float var = stats[D + j] * Ninv - mu * mu;
        float inv = rsqrtf(var + EPSV);
        float s = gamma[j] * inv;
        sc[j] = s;
        sh[j] = beta[j] - mu * s;
    }
    __syncthreads();
    long long i = (long long)blockIdx.x * blockDim.x + threadIdx.x;
    const long long stride = (long long)gridDim.x * blockDim.x;
    for (; i < total4; i += stride) {
        f16x4 v = reinterpret_cast<const f16x4*>(t)[i];
        int f0 = (int)((i * 4) & (D - 1));
        float4 o;
        o.x = (float)v[0] * sc[f0 + 0] + sh[f0 + 0];
        o.y = (float)v[1] * sc[f0 + 1] + sh[f0 + 1];
        o.z = (float)v[2] * sc[f0 + 2] + sh[f0 + 2];
        o.w = (float)v[3] * sc[f0 + 3] + sh[f0 + 3];
        reinterpret_cast<float4*>(out)[i] = o;
    }
}

extern "C" void kernel_launch(void* const* d_in, const int* in_sizes, int n_in,
                              void* d_out, int out_size, void* d_ws, size_t ws_size,
                              hipStream_t stream)
{
    const float* x_in  = (const float*)d_in[0];
    const int*   ei    = (const int*)d_in[1];
    const float* W     = (const float*)d_in[2];
    const float* bias  = (const float*)d_in[3];
    const float* gamma = (const float*)d_in[4];
    const float* beta  = (const float*)d_in[5];

    const int N = in_sizes[0] / D;
    const int E = in_sizes[1] / 2;
    const int L = in_sizes[2] / (D * D);
    const int* row = ei;           // source
    const int* col = ei + E;       // target
    const int NBUCK = (N + 255) >> 8;
    const int seg = NBUCK * 8;
    const int nrg = (N + 15) / 16;

    // ws layout: [f16: tbuf | hbuf | Wfo] [f32: dis | stats | shW]
    //            [int4: nodeinfo] [int: srcs | gb | soff | cur | bpairs]
    f16* tbuf = (f16*)d_ws;
    f16* hbuf = tbuf + (size_t)N * D;
    f16* Wfo  = hbuf + (size_t)N * D;
    float* dis   = (float*)(Wfo + D * D);
    float* stats = dis + N;
    float* shW   = stats + 2 * D;
    size_t offf = (size_t)(shW + D - (float*)d_ws);
    offf = (offf + 3) & ~(size_t)3;                  // 16B align
    int4* nodeinfo = (int4*)((float*)d_ws + offf);
    int* srcs   = (int*)(nodeinfo + (size_t)NBUCK * 256);
    int* gb     = srcs + (E + 16);
    int* soff   = gb + 4096;
    int* cur    = soff + 4097;
    int* bpairs = cur + 4096 * 16;

    // ---- CSR build (5 dispatches) ----
    hipMemsetAsync(gb, 0, 4096 * sizeof(int), stream);
    bcount_kernel<<<128, 256, 0, stream>>>(col, gb, E, seg);
    bscan_kernel<<<1, 1024, 0, stream>>>(gb, soff, cur);
    bfill_kernel<<<1024, 256, 0, stream>>>(row, col, cur, bpairs, E);
    build_kernel<<<NBUCK, 256, 0, stream>>>(bpairs, soff, dis, nodeinfo, srcs, N);

    const float Ninv = 1.0f / (float)N;
    const long long total4 = (long long)N * D / 4;
    const int gblocks = (N + 63) / 64;    // 32 nodes/iter, exactly 2 iterations

    fold_kernel<<<D, D, 0, stream>>>(W, stats, gamma, beta, Ninv, 1, Wfo, shW);

    for (int l = 0; l < L; l++) {
        gemm_kernel<<<512, 256, 0, stream>>>(
            tbuf, (l == 0) ? x_in : nullptr, Wfo, shW, dis, hbuf, stats, N, nrg);
        gather_kernel<<<gblocks, 256, 0, stream>>>(
            hbuf, nodeinfo, srcs, bias + (size_t)l * D, tbuf, stats, N, E);
        if (l < L - 1)
            fold_kernel<<<D, D, 0, stream>>>(
                W + (size_t)(l + 1) * D * D, stats, gamma + (size_t)(l + 1) * D,
                beta + (size_t)(l + 1) * D, Ninv, 0, Wfo, shW);
        else
            epi2_kernel<<<4096, 256, 0, stream>>>(
                tbuf, stats, gamma + (size_t)l * D, beta + (size_t)l * D,
                Ninv, (float*)d_out, total4);
    }
}